// Round 11
// baseline (324.687 us; speedup 1.0000x reference)
//
#include <hip/hip_runtime.h>

typedef unsigned short u16;
typedef short bf16x8 __attribute__((ext_vector_type(8)));
typedef float f32x4 __attribute__((ext_vector_type(4)));

__device__ __forceinline__ float bf2f(u16 u) {
    union { unsigned int i; float f; } v; v.i = ((unsigned int)u) << 16; return v.f;
}
__device__ __forceinline__ u16 f2bf(float f) {
    union { float f; unsigned int i; } v; v.f = f;
    unsigned int r = v.i + 0x7fffu + ((v.i >> 16) & 1u);
    return (u16)(r >> 16);
}
__device__ __forceinline__ float gelu(float u) {
    float y = 0.7978845608028654f * (u + 0.044715f * u * u * u);
    float t = __expf(2.0f * y);
    return 0.5f * u * (1.0f + (1.0f - 2.0f / (t + 1.0f)));
}

// async global->LDS, 16B per lane. LDS dest is wave-uniform base + lane*16.
__device__ __forceinline__ void gload16(const u16* g, u16* l) {
    __builtin_amdgcn_global_load_lds((__attribute__((address_space(1))) void*)(u16*)g,
                                     (__attribute__((address_space(3))) void*)l, 16, 0, 0);
}

// ---------------------------------------------------------------------------
// Fused prep: 5 weight transposes (fp32 -> bf16) + q/v bias concat + LN1.
// ---------------------------------------------------------------------------
__global__ __launch_bounds__(256) void prep(const float* __restrict__ Wq,
                                            const float* __restrict__ Wv,
                                            const float* __restrict__ Wo,
                                            const float* __restrict__ W1,
                                            const float* __restrict__ W2,
                                            const float* __restrict__ bq,
                                            const float* __restrict__ bv,
                                            const float* __restrict__ x,
                                            const float* __restrict__ g1,
                                            const float* __restrict__ be1,
                                            u16* __restrict__ WqT, u16* __restrict__ WvT,
                                            u16* __restrict__ WoT, u16* __restrict__ W1T,
                                            u16* __restrict__ W2T, float* __restrict__ bqv,
                                            u16* __restrict__ h1) {
    int id = blockIdx.x;
    int tid = threadIdx.x;
    if (id >= 2824) {            // LN1: one row per block
        int row = id - 2824;
        int lane = tid & 63, wave = tid >> 6;
        float4 f4 = *(const float4*)(x + (size_t)row * 1024 + tid * 4);
        float v[4] = {f4.x, f4.y, f4.z, f4.w};
        float s1 = v[0] + v[1] + v[2] + v[3];
        float s2 = v[0]*v[0] + v[1]*v[1] + v[2]*v[2] + v[3]*v[3];
#pragma unroll
        for (int mm = 1; mm < 64; mm <<= 1) { s1 += __shfl_xor(s1, mm); s2 += __shfl_xor(s2, mm); }
        __shared__ float a1[4], a2[4];
        if (lane == 0) { a1[wave] = s1; a2[wave] = s2; }
        __syncthreads();
        s1 = a1[0] + a1[1] + a1[2] + a1[3];
        s2 = a2[0] + a2[1] + a2[2] + a2[3];
        float mean = s1 * (1.0f / 1024.0f);
        float var  = s2 * (1.0f / 1024.0f) - mean * mean;
        float rstd = rsqrtf(var + 1e-5f);
#pragma unroll
        for (int i = 0; i < 4; ++i) {
            int c = tid * 4 + i;
            h1[(size_t)row * 1024 + c] = f2bf((v[i] - mean) * rstd * g1[c] + be1[c]);
        }
        return;
    }
    if (id >= 2816) {
        int i = (id - 2816) * 256 + tid;
        bqv[i] = (i < 1024) ? bq[i] : bv[i - 1024];
        return;
    }
    const float* in; u16* out; int R, C, bx, by;
    if (id < 256)       { in = Wq; out = WqT; R = 1024; C = 1024; bx = id & 15;          by = id >> 4; }
    else if (id < 512)  { int t = id - 256;  in = Wv; out = WvT; R = 1024; C = 1024; bx = t & 15; by = t >> 4; }
    else if (id < 768)  { int t = id - 512;  in = Wo; out = WoT; R = 1024; C = 1024; bx = t & 15; by = t >> 4; }
    else if (id < 1792) { int t = id - 768;  in = W1; out = W1T; R = 1024; C = 4096; bx = t & 63; by = t >> 6; }
    else                { int t = id - 1792; in = W2; out = W2T; R = 4096; C = 1024; bx = t & 15; by = t >> 4; }
    __shared__ u16 tile[64][65];
    int c0 = bx * 64, r0 = by * 64;
    for (int i = tid; i < 4096; i += 256) {
        int r = i >> 6, c = i & 63;
        tile[r][c] = f2bf(in[(size_t)(r0 + r) * C + c0 + c]);
    }
    __syncthreads();
    for (int i = tid; i < 4096; i += 256) {
        int r = i >> 6, c = i & 63;
        out[(size_t)(c0 + r) * R + r0 + c] = tile[c][r];
    }
}

// ---------------------------------------------------------------------------
// bf16 transpose with input row stride (V columns of QV): out[c][r]=in[r][c].
// ---------------------------------------------------------------------------
__global__ __launch_bounds__(256) void transpose_bf16_s(const u16* __restrict__ in,
                                                        u16* __restrict__ out,
                                                        int R, int C, int istride) {
    __shared__ u16 tile[64][65];
    int c0 = blockIdx.x * 64, r0 = blockIdx.y * 64;
    in  += (size_t)blockIdx.z * R * istride;
    out += (size_t)blockIdx.z * R * C;
    for (int i = threadIdx.x; i < 4096; i += 256) {
        int r = i >> 6, c = i & 63;
        tile[r][c] = in[(size_t)(r0 + r) * istride + c0 + c];
    }
    __syncthreads();
    for (int i = threadIdx.x; i < 4096; i += 256) {
        int r = i >> 6, c = i & 63;
        out[(size_t)(c0 + r) * R + r0 + c] = tile[c][r];
    }
}

// ---------------------------------------------------------------------------
// LayerNorm over 1024 cols (bf16 in, bf16 out), one row per block.
// ---------------------------------------------------------------------------
__global__ __launch_bounds__(256) void ln_bf16(const u16* __restrict__ x,
                                               const float* __restrict__ g,
                                               const float* __restrict__ be,
                                               u16* __restrict__ out) {
    int row = blockIdx.x, tid = threadIdx.x;
    int lane = tid & 63, wave = tid >> 6;
    u16 e[4]; *(uint2*)e = *(const uint2*)(x + (size_t)row * 1024 + tid * 4);
    float v[4];
#pragma unroll
    for (int i = 0; i < 4; ++i) v[i] = bf2f(e[i]);
    float s1 = v[0] + v[1] + v[2] + v[3];
    float s2 = v[0]*v[0] + v[1]*v[1] + v[2]*v[2] + v[3]*v[3];
#pragma unroll
    for (int mm = 1; mm < 64; mm <<= 1) { s1 += __shfl_xor(s1, mm); s2 += __shfl_xor(s2, mm); }
    __shared__ float a1[4], a2[4];
    if (lane == 0) { a1[wave] = s1; a2[wave] = s2; }
    __syncthreads();
    s1 = a1[0] + a1[1] + a1[2] + a1[3];
    s2 = a2[0] + a2[1] + a2[2] + a2[3];
    float mean = s1 * (1.0f / 1024.0f);
    float var  = s2 * (1.0f / 1024.0f) - mean * mean;
    float rstd = rsqrtf(var + 1e-5f);
#pragma unroll
    for (int i = 0; i < 4; ++i) {
        int c = tid * 4 + i;
        out[(size_t)row * 1024 + c] = f2bf((v[i] - mean) * rstd * g[c] + be[c]);
    }
}

// ---------------------------------------------------------------------------
// GEMM 128xBN (m97 + XOR swizzle + XCD swizzle + coalesced LDS epilogue).
// ---------------------------------------------------------------------------
template <int BN, int ACT, int RES>
__global__ __launch_bounds__(256) void gemm_gl(const u16* __restrict__ A,
                                               const u16* __restrict__ WT,
                                               const float* __restrict__ bias,
                                               const float* __restrict__ resid,
                                               u16* __restrict__ C,
                                               int M, int N, int K, int cpx) {
    constexpr int JN = BN / 32;
    constexpr int TS = BN + 8;           // padded epilogue stride
    __shared__ u16 lds_a[128 * 64];      // 16 KB (also epilogue tile, 32*TS)
    __shared__ u16 lds_b[BN * 64];
    int tid = threadIdx.x;
    int lane = tid & 63, wave = tid >> 6;
    int l16 = lane & 15, quad = lane >> 4;
    int wm = (wave >> 1) * 64, wn = (wave & 1) * (BN / 2);

    int id = blockIdx.x;
    int slot = id >> 3;
    int bx = (id & 7) * cpx + (slot >> 5);
    int by = slot & 31;
    int m0 = by * 128, n0 = bx * BN;
    f32x4 acc[4][JN] = {};

    int scol = ((lane & 7) ^ (lane >> 3)) * 8;
    const u16* Ab = A  + (size_t)(m0 + wave * 8 + (lane >> 3)) * K + scol;
    const u16* Bb = WT + (size_t)(n0 + wave * 8 + (lane >> 3)) * K + scol;
    u16* la = lds_a + wave * 512;
    u16* lb = lds_b + wave * 512;
    int xk = (l16 & 7);

    for (int k0 = 0; k0 < K; k0 += 64) {
        __syncthreads();
#pragma unroll
        for (int it = 0; it < 4; ++it)
            gload16(Ab + (size_t)it * 32 * K + k0, la + it * 2048);
#pragma unroll
        for (int it = 0; it < JN; ++it)
            gload16(Bb + (size_t)it * 32 * K + k0, lb + it * 2048);
        __syncthreads();
#pragma unroll
        for (int s = 0; s < 2; ++s) {
            bf16x8 af[4], bfr[JN];
#pragma unroll
            for (int i = 0; i < 4; ++i)
                af[i] = *(const bf16x8*)&lds_a[(wm + i * 16 + l16) * 64 + (((s * 4 + quad) ^ xk) * 8)];
#pragma unroll
            for (int j = 0; j < JN; ++j)
                bfr[j] = *(const bf16x8*)&lds_b[(wn + j * 16 + l16) * 64 + (((s * 4 + quad) ^ xk) * 8)];
#pragma unroll
            for (int i = 0; i < 4; ++i)
#pragma unroll
                for (int j = 0; j < JN; ++j)
                    acc[i][j] = __builtin_amdgcn_mfma_f32_16x16x32_bf16(af[i], bfr[j], acc[i][j], 0, 0, 0);
        }
    }

    // Coalesced epilogue: 4 passes of a 32 x BN bf16 slab through LDS.
    u16* et = lds_a;
    int erow = tid >> 3;                       // 0..31
    int lr0  = (wave >> 1) * 16 + quad * 4;
    float bvj[JN];
#pragma unroll
    for (int j = 0; j < JN; ++j) bvj[j] = bias[n0 + wn + j * 16 + l16];
#pragma unroll
    for (int i = 0; i < 4; ++i) {
        __syncthreads();
#pragma unroll
        for (int j = 0; j < JN; ++j) {
            int col = wn + j * 16 + l16;
#pragma unroll
            for (int r = 0; r < 4; ++r) {
                float v = acc[i][j][r] + bvj[j];
                if (ACT) v = gelu(v);
                if (RES) v += resid[(size_t)(m0 + wm + i * 16 + quad * 4 + r) * N + n0 + col];
                et[(lr0 + r) * TS + col] = f2bf(v);
            }
        }
        __syncthreads();
        int grow = m0 + (erow >> 4) * 64 + i * 16 + (erow & 15);
        if (BN == 128) {
            int ec = (tid & 7) * 16;           // 32 B per thread
            uint4 d0 = *(const uint4*)&et[erow * TS + ec];
            uint4 d1 = *(const uint4*)&et[erow * TS + ec + 8];
            *(uint4*)&C[(size_t)grow * N + n0 + ec]     = d0;
            *(uint4*)&C[(size_t)grow * N + n0 + ec + 8] = d1;
        } else {                               // BN == 64: 16 B per thread
            int ec = (tid & 7) * 8;
            uint4 d0 = *(const uint4*)&et[erow * TS + ec];
            *(uint4*)&C[(size_t)grow * N + n0 + ec] = d0;
        }
    }
}

// ---------------------------------------------------------------------------
// Big-tile GEMM (FF1): 256x128 tile, acc 8x4, coalesced LDS epilogue.
// launch_bounds(256,3): 3 blocks/CU (144 KB LDS) for barrier-drain overlap.
// ---------------------------------------------------------------------------
template <int ACT>
__global__ __launch_bounds__(256, 3) void gemm_big(const u16* __restrict__ A,
                                                   const u16* __restrict__ WT,
                                                   const float* __restrict__ bias,
                                                   u16* __restrict__ C,
                                                   int M, int N, int K) {
    __shared__ u16 lds_a[256 * 64];      // 32 KB (also epilogue tile)
    __shared__ u16 lds_b[128 * 64];      // 16 KB
    int tid = threadIdx.x;
    int lane = tid & 63, wave = tid >> 6;
    int l16 = lane & 15, quad = lane >> 4;
    int wm = (wave >> 1) * 128, wn = (wave & 1) * 64;
    int id = blockIdx.x;
    int bx = id & 31, by = id >> 5;
    int m0 = by * 256, n0 = bx * 128;
    f32x4 acc[8][4] = {};

    int scol = ((lane & 7) ^ (lane >> 3)) * 8;
    const u16* Ab = A  + (size_t)(m0 + wave * 8 + (lane >> 3)) * K + scol;
    const u16* Bb = WT + (size_t)(n0 + wave * 8 + (lane >> 3)) * K + scol;
    u16* la = lds_a + wave * 512;
    u16* lb = lds_b + wave * 512;
    int xk = (l16 & 7);

    for (int k0 = 0; k0 < K; k0 += 64) {
        __syncthreads();
#pragma unroll
        for (int it = 0; it < 8; ++it)
            gload16(Ab + (size_t)it * 32 * K + k0, la + it * 2048);
#pragma unroll
        for (int it = 0; it < 4; ++it)
            gload16(Bb + (size_t)it * 32 * K + k0, lb + it * 2048);
        __syncthreads();
#pragma unroll
        for (int s = 0; s < 2; ++s) {
            bf16x8 bfr[4];
#pragma unroll
            for (int j = 0; j < 4; ++j)
                bfr[j] = *(const bf16x8*)&lds_b[(wn + j * 16 + l16) * 64 + (((s * 4 + quad) ^ xk) * 8)];
#pragma unroll
            for (int i = 0; i < 8; ++i) {
                bf16x8 af = *(const bf16x8*)&lds_a[(wm + i * 16 + l16) * 64 + (((s * 4 + quad) ^ xk) * 8)];
#pragma unroll
                for (int j = 0; j < 4; ++j)
                    acc[i][j] = __builtin_amdgcn_mfma_f32_16x16x32_bf16(af, bfr[j], acc[i][j], 0, 0, 0);
            }
        }
    }

    // Coalesced epilogue: 8 passes of a 32x128 bf16 slab through LDS.
    constexpr int TS = 136;
    u16* et = lds_a;
    int erow = tid >> 3;
    int ec   = (tid & 7) * 16;
    int lr0  = (wave >> 1) * 16 + quad * 4;
    float bvj[4];
#pragma unroll
    for (int j = 0; j < 4; ++j) bvj[j] = bias[n0 + wn + j * 16 + l16];
#pragma unroll
    for (int i = 0; i < 8; ++i) {
        __syncthreads();
#pragma unroll
        for (int j = 0; j < 4; ++j) {
            int col = wn + j * 16 + l16;
#pragma unroll
            for (int r = 0; r < 4; ++r) {
                float v = acc[i][j][r] + bvj[j];
                if (ACT) v = gelu(v);
                et[(lr0 + r) * TS + col] = f2bf(v);
            }
        }
        __syncthreads();
        int grow = m0 + (erow >> 4) * 128 + i * 16 + (erow & 15);
        uint4 d0 = *(const uint4*)&et[erow * TS + ec];
        uint4 d1 = *(const uint4*)&et[erow * TS + ec + 8];
        *(uint4*)&C[(size_t)grow * N + n0 + ec]     = d0;
        *(uint4*)&C[(size_t)grow * N + n0 + ec + 8] = d1;
    }
}

// ---------------------------------------------------------------------------
// FF2 split-K GEMM: 256x128 tiles, split-K=3, bf16 partials, coalesced epi.
// A-LOCAL XCD map: xcd = id&7 owns by in {2*xcd, 2*xcd+1} for all (bx,slice)
// => each ff1 A-panel is read on exactly ONE XCD (L2-resident, reused 8x).
// launch_bounds(256,3) for barrier-drain overlap.
// ---------------------------------------------------------------------------
__global__ __launch_bounds__(256, 3) void gemm_split(const u16* __restrict__ A,
                                                     const u16* __restrict__ WT,
                                                     u16* __restrict__ p0,
                                                     u16* __restrict__ p1,
                                                     u16* __restrict__ p2,
                                                     int M, int N, int K) {
    __shared__ u16 lds_a[256 * 64];
    __shared__ u16 lds_b[128 * 64];
    int tid = threadIdx.x;
    int lane = tid & 63, wave = tid >> 6;
    int l16 = lane & 15, quad = lane >> 4;
    int wm = (wave >> 1) * 128, wn = (wave & 1) * 64;
    int id = blockIdx.x;
    int u = id >> 3;                     // 0..47
    int by = (id & 7) * 2 + (u & 1);     // A-panel owned by xcd = id&7
    int bx = (u >> 1) & 7;
    int slice = u >> 4;                  // 0..2
    int m0 = by * 256, n0 = bx * 128;
    int k_lo = (slice == 0) ? 0 : 64 * (22 + 21 * (slice - 1));
    int k_hi = (slice == 2) ? K : 64 * (22 + 21 * slice);
    u16* P = (slice == 0) ? p0 : (slice == 1) ? p1 : p2;
    f32x4 acc[8][4] = {};

    int scol = ((lane & 7) ^ (lane >> 3)) * 8;
    const u16* Ab = A  + (size_t)(m0 + wave * 8 + (lane >> 3)) * K + scol;
    const u16* Bb = WT + (size_t)(n0 + wave * 8 + (lane >> 3)) * K + scol;
    u16* la = lds_a + wave * 512;
    u16* lb = lds_b + wave * 512;
    int xk = (l16 & 7);

    for (int k0 = k_lo; k0 < k_hi; k0 += 64) {
        __syncthreads();
#pragma unroll
        for (int it = 0; it < 8; ++it)
            gload16(Ab + (size_t)it * 32 * K + k0, la + it * 2048);
#pragma unroll
        for (int it = 0; it < 4; ++it)
            gload16(Bb + (size_t)it * 32 * K + k0, lb + it * 2048);
        __syncthreads();
#pragma unroll
        for (int s = 0; s < 2; ++s) {
            bf16x8 bfr[4];
#pragma unroll
            for (int j = 0; j < 4; ++j)
                bfr[j] = *(const bf16x8*)&lds_b[(wn + j * 16 + l16) * 64 + (((s * 4 + quad) ^ xk) * 8)];
#pragma unroll
            for (int i = 0; i < 8; ++i) {
                bf16x8 af = *(const bf16x8*)&lds_a[(wm + i * 16 + l16) * 64 + (((s * 4 + quad) ^ xk) * 8)];
#pragma unroll
                for (int j = 0; j < 4; ++j)
                    acc[i][j] = __builtin_amdgcn_mfma_f32_16x16x32_bf16(af, bfr[j], acc[i][j], 0, 0, 0);
            }
        }
    }

    constexpr int TS = 136;
    u16* et = lds_a;
    int erow = tid >> 3;
    int ec   = (tid & 7) * 16;
    int lr0  = (wave >> 1) * 16 + quad * 4;
#pragma unroll
    for (int i = 0; i < 8; ++i) {
        __syncthreads();
#pragma unroll
        for (int j = 0; j < 4; ++j) {
            int col = wn + j * 16 + l16;
#pragma unroll
            for (int r = 0; r < 4; ++r)
                et[(lr0 + r) * TS + col] = f2bf(acc[i][j][r]);
        }
        __syncthreads();
        int grow = m0 + (erow >> 4) * 128 + i * 16 + (erow & 15);
        uint4 d0 = *(const uint4*)&et[erow * TS + ec];
        uint4 d1 = *(const uint4*)&et[erow * TS + ec + 8];
        *(uint4*)&P[(size_t)grow * N + n0 + ec]     = d0;
        *(uint4*)&P[(size_t)grow * N + n0 + ec + 8] = d1;
    }
}

// ---------------------------------------------------------------------------
// FF2 reduce: out = x2b(bf16) + p0 + p1 + p2 + b2.  fp32 out.
// ---------------------------------------------------------------------------
__global__ __launch_bounds__(256) void ff2_reduce(const u16* __restrict__ p0,
                                                  const u16* __restrict__ p1,
                                                  const u16* __restrict__ p2,
                                                  const u16* __restrict__ x2b,
                                                  const float* __restrict__ b2,
                                                  float* __restrict__ out) {
    size_t i = ((size_t)blockIdx.x * 256 + threadIdx.x) * 8;
    int col = (int)(i & 1023);
    uint4 a0 = *(const uint4*)&p0[i];
    uint4 a1 = *(const uint4*)&p1[i];
    uint4 a2 = *(const uint4*)&p2[i];
    uint4 ax = *(const uint4*)&x2b[i];
    const u16* e0 = (const u16*)&a0;
    const u16* e1 = (const u16*)&a1;
    const u16* e2 = (const u16*)&a2;
    const u16* ex = (const u16*)&ax;
    float o[8];
#pragma unroll
    for (int e = 0; e < 8; ++e)
        o[e] = bf2f(ex[e]) + bf2f(e0[e]) + bf2f(e1[e]) + bf2f(e2[e]) + b2[col + e];
    *(float4*)&out[i]     = *(float4*)&o[0];
    *(float4*)&out[i + 4] = *(float4*)&o[4];
}

// ---------------------------------------------------------------------------
// Causal attention, Q==K, no-max softmax. Q/K from QV [4096][2048] (Q cols
// 0..1023); V pre-transposed Vt[b,h,d,s]. 1024 blocks = 4/CU, longest-first.
// ---------------------------------------------------------------------------
__global__ __launch_bounds__(256) void attn_kernel(const u16* __restrict__ QV,
                                                   const u16* __restrict__ Vt,
                                                   u16* __restrict__ Out) {
    int id = blockIdx.x;
    int slot = id >> 3;
    int hb = (id & 7) + 8 * (slot & 3);
    int t  = 31 - (slot >> 2);
    int h = hb & 15, b = hb >> 4;
    int tid = threadIdx.x;
    int lane = tid & 63, wave = tid >> 6;
    int l16 = lane & 15, quad = lane >> 4;

    __shared__ u16 k_lds[64 * 64];
    __shared__ u16 v_lds[64 * 64];
    __shared__ u16 p_lds[4][16 * 72];

    bf16x8 ones;
#pragma unroll
    for (int e = 0; e < 8; ++e) ones[e] = (short)0x3F80;

    int srow = wave * 8 + (lane >> 3);
    int sc8  = ((lane & 7) ^ (lane >> 3)) * 8;
    int xk   = (l16 & 7);

    int q0 = t * 64;
    const u16* qp = QV + ((size_t)b * 2048 + q0 + wave * 16 + l16) * 2048 + h * 64;
    bf16x8 qf[2];
    qf[0] = *(const bf16x8*)&qp[quad * 8];
    qf[1] = *(const bf16x8*)&qp[32 + quad * 8];

    f32x4 O[4] = {};
    f32x4 L = {};

    for (int kt = 0; kt <= t; ++kt) {
        const u16* kg = QV + ((size_t)b * 2048 + kt * 64 + srow) * 2048 + h * 64 + sc8;
        const u16* vg = Vt + ((((size_t)b * 16 + h) * 64) + srow) * 2048 + kt * 64 + sc8;
        __syncthreads();
        gload16(kg,                      k_lds + wave * 512);
        gload16(kg + (size_t)32 * 2048,  k_lds + wave * 512 + 2048);
        gload16(vg,                      v_lds + wave * 512);
        gload16(vg + (size_t)32 * 2048,  v_lds + wave * 512 + 2048);
        __syncthreads();

        f32x4 S[4] = {};
#pragma unroll
        for (int s = 0; s < 2; ++s)
#pragma unroll
            for (int j = 0; j < 4; ++j) {
                bf16x8 kf = *(const bf16x8*)&k_lds[(j * 16 + l16) * 64 + (((s * 4 + quad) ^ xk) * 8)];
                S[j] = __builtin_amdgcn_mfma_f32_16x16x32_bf16(qf[s], kf, S[j], 0, 0, 0);
            }

        if (kt == t) {
#pragma unroll
            for (int j = 0; j < 4; ++j) {
                int key = j * 16 + l16;
#pragma unroll
                for (int r = 0; r < 4; ++r)
                    if (key > wave * 16 + quad * 4 + r) S[j][r] = -1e30f;
            }
        }

#pragma unroll
        for (int j = 0; j < 4; ++j)
#pragma unroll
            for (int r = 0; r < 4; ++r) {
                float pp = __expf(S[j][r] * 0.125f);
                p_lds[wave][(quad * 4 + r) * 72 + j * 16 + l16] = f2bf(pp);
            }

#pragma unroll
        for (int s = 0; s < 2; ++s) {
            bf16x8 pf = *(const bf16x8*)&p_lds[wave][l16 * 72 + s * 32 + quad * 8];
            L = __builtin_amdgcn_mfma_f32_16x16x32_bf16(pf, ones, L, 0, 0, 0);
#pragma unroll
            for (int dj = 0; dj < 4; ++dj) {
                bf16x8 vf = *(const bf16x8*)&v_lds[(dj * 16 + l16) * 64 + (((s * 4 + quad) ^ xk) * 8)];
                O[dj] = __builtin_amdgcn_mfma_f32_16x16x32_bf16(pf, vf, O[dj], 0, 0, 0);
            }
        }
    }

#pragma unroll
    for (int r = 0; r < 4; ++r) {
        int qg = q0 + wave * 16 + quad * 4 + r;
        float inv = 1.0f / L[r];
#pragma unroll
        for (int dj = 0; dj < 4; ++dj)
            Out[((size_t)b * 2048 + qg) * 1024 + h * 64 + dj * 16 + l16] =
                f2bf(O[dj][r] * inv);
    }
}

// ---------------------------------------------------------------------------
extern "C" void kernel_launch(void* const* d_in, const int* in_sizes, int n_in,
                              void* d_out, int out_size, void* d_ws, size_t ws_size,
                              hipStream_t stream) {
    const float* x   = (const float*)d_in[0];
    const float* Wq  = (const float*)d_in[1];
    const float* bq  = (const float*)d_in[2];
    const float* Wv  = (const float*)d_in[3];
    const float* bv  = (const float*)d_in[4];
    const float* Wo  = (const float*)d_in[5];
    const float* bo  = (const float*)d_in[6];
    const float* W1  = (const float*)d_in[7];
    const float* b1  = (const float*)d_in[8];
    const float* W2  = (const float*)d_in[9];
    const float* b2  = (const float*)d_in[10];
    const float* g1  = (const float*)d_in[11];
    const float* be1 = (const float*)d_in[12];
    const float* g2  = (const float*)d_in[13];
    const float* be2 = (const float*)d_in[14];

    char* ws = (char*)d_ws;
    const size_t MB = 1 << 20;
    // Map:  0-2 WqT | 2-4 WvT | 4-6 WoT | 6-14 W1T | 14-22 W2T
    // 22-30 h1 (LN1 / attn out / h2) | 30-46 QV -> 30-38 x2b after attn
    // 46-54 Vt -> 46-78 ff1 after attn | fp0@0 fp1@22 fp2@38 | bqv@78
    u16*   WqT  = (u16*)(ws + 0  * MB);
    u16*   WvT  = (u16*)(ws + 2  * MB);
    u16*   WoT  = (u16*)(ws + 4  * MB);
    u16*   W1T  = (u16*)(ws + 6  * MB);
    u16*   W2T  = (u16*)(ws + 14 * MB);
    u16*   h1   = (u16*)(ws + 22 * MB);
    u16*   QV   = (u16*)(ws + 30 * MB);
    u16*   x2b  = (u16*)(ws + 30 * MB);
    u16*   Vt   = (u16*)(ws + 46 * MB);
    u16*   ff1  = (u16*)(ws + 46 * MB);
    float* bqv  = (float*)(ws + 78 * MB);
    u16*   fp0  = (u16*)(ws + 0  * MB);
    u16*   fp1  = (u16*)(ws + 22 * MB);
    u16*   fp2  = (u16*)(ws + 38 * MB);

    // 1. fused weight transposes + bias concat + LN1
    prep<<<6920, 256, 0, stream>>>(Wq, Wv, Wo, W1, W2, bq, bv, x, g1, be1,
                                   WqT, WvT, WoT, W1T, W2T, bqv, h1);

    // 2. QV = h1 @ [Wq|Wv] + [bq|bv]   (BN=128, 512 blocks, cpx=2)
    gemm_gl<128, 0, 0><<<512, 256, 0, stream>>>(h1, WqT, bqv, nullptr, QV, 4096, 2048, 1024, 2);

    // 3. Vt[b,h,d,s] = transpose of V columns of QV (coalesced LDS transpose)
    transpose_bf16_s<<<dim3(16, 32, 2), 256, 0, stream>>>(QV + 1024, Vt, 2048, 1024, 2048);

    // 4. attention -> h1
    attn_kernel<<<1024, 256, 0, stream>>>(QV, Vt, h1);

    // 5. x2b = bf16(x + attn_out@Wo + bo)
    gemm_gl<64, 0, 1><<<512, 256, 0, stream>>>(h1, WoT, bo, x, x2b, 4096, 1024, 1024, 2);

    // 6. h2 = LN2(x2b) -> h1
    ln_bf16<<<4096, 256, 0, stream>>>(x2b, g2, be2, h1);

    // 7. ff1 = gelu(h2@W1 + b1)
    gemm_big<1><<<512, 256, 0, stream>>>(h1, W1T, b1, ff1, 4096, 4096, 1024);

    // 8. FF2 split-K partials (A-local XCD map)
    gemm_split<<<384, 256, 0, stream>>>(ff1, W2T, fp0, fp1, fp2, 4096, 1024, 4096);

    // 9. out = x2b + p0+p1+p2 + b2  (fp32)
    ff2_reduce<<<2048, 256, 0, stream>>>(fp0, fp1, fp2, x2b, b2, (float*)d_out);
}

// Round 12
// 314.229 us; speedup vs baseline: 1.0333x; 1.0333x over previous
//
#include <hip/hip_runtime.h>

typedef unsigned short u16;
typedef short bf16x8 __attribute__((ext_vector_type(8)));
typedef float f32x4 __attribute__((ext_vector_type(4)));

__device__ __forceinline__ float bf2f(u16 u) {
    union { unsigned int i; float f; } v; v.i = ((unsigned int)u) << 16; return v.f;
}
__device__ __forceinline__ u16 f2bf(float f) {
    union { float f; unsigned int i; } v; v.f = f;
    unsigned int r = v.i + 0x7fffu + ((v.i >> 16) & 1u);
    return (u16)(r >> 16);
}
__device__ __forceinline__ float gelu(float u) {
    float y = 0.7978845608028654f * (u + 0.044715f * u * u * u);
    float t = __expf(2.0f * y);
    return 0.5f * u * (1.0f + (1.0f - 2.0f / (t + 1.0f)));
}

// async global->LDS, 16B per lane. LDS dest is wave-uniform base + lane*16.
__device__ __forceinline__ void gload16(const u16* g, u16* l) {
    __builtin_amdgcn_global_load_lds((__attribute__((address_space(1))) void*)(u16*)g,
                                     (__attribute__((address_space(3))) void*)l, 16, 0, 0);
}

// ---------------------------------------------------------------------------
// Fused prep: 5 weight transposes (fp32 -> bf16) + q/v bias concat + LN1.
// ---------------------------------------------------------------------------
__global__ __launch_bounds__(256) void prep(const float* __restrict__ Wq,
                                            const float* __restrict__ Wv,
                                            const float* __restrict__ Wo,
                                            const float* __restrict__ W1,
                                            const float* __restrict__ W2,
                                            const float* __restrict__ bq,
                                            const float* __restrict__ bv,
                                            const float* __restrict__ x,
                                            const float* __restrict__ g1,
                                            const float* __restrict__ be1,
                                            u16* __restrict__ WqT, u16* __restrict__ WvT,
                                            u16* __restrict__ WoT, u16* __restrict__ W1T,
                                            u16* __restrict__ W2T, float* __restrict__ bqv,
                                            u16* __restrict__ h1) {
    int id = blockIdx.x;
    int tid = threadIdx.x;
    if (id >= 2824) {            // LN1: one row per block
        int row = id - 2824;
        int lane = tid & 63, wave = tid >> 6;
        float4 f4 = *(const float4*)(x + (size_t)row * 1024 + tid * 4);
        float v[4] = {f4.x, f4.y, f4.z, f4.w};
        float s1 = v[0] + v[1] + v[2] + v[3];
        float s2 = v[0]*v[0] + v[1]*v[1] + v[2]*v[2] + v[3]*v[3];
#pragma unroll
        for (int mm = 1; mm < 64; mm <<= 1) { s1 += __shfl_xor(s1, mm); s2 += __shfl_xor(s2, mm); }
        __shared__ float a1[4], a2[4];
        if (lane == 0) { a1[wave] = s1; a2[wave] = s2; }
        __syncthreads();
        s1 = a1[0] + a1[1] + a1[2] + a1[3];
        s2 = a2[0] + a2[1] + a2[2] + a2[3];
        float mean = s1 * (1.0f / 1024.0f);
        float var  = s2 * (1.0f / 1024.0f) - mean * mean;
        float rstd = rsqrtf(var + 1e-5f);
#pragma unroll
        for (int i = 0; i < 4; ++i) {
            int c = tid * 4 + i;
            h1[(size_t)row * 1024 + c] = f2bf((v[i] - mean) * rstd * g1[c] + be1[c]);
        }
        return;
    }
    if (id >= 2816) {
        int i = (id - 2816) * 256 + tid;
        bqv[i] = (i < 1024) ? bq[i] : bv[i - 1024];
        return;
    }
    const float* in; u16* out; int R, C, bx, by;
    if (id < 256)       { in = Wq; out = WqT; R = 1024; C = 1024; bx = id & 15;          by = id >> 4; }
    else if (id < 512)  { int t = id - 256;  in = Wv; out = WvT; R = 1024; C = 1024; bx = t & 15; by = t >> 4; }
    else if (id < 768)  { int t = id - 512;  in = Wo; out = WoT; R = 1024; C = 1024; bx = t & 15; by = t >> 4; }
    else if (id < 1792) { int t = id - 768;  in = W1; out = W1T; R = 1024; C = 4096; bx = t & 63; by = t >> 6; }
    else                { int t = id - 1792; in = W2; out = W2T; R = 4096; C = 1024; bx = t & 15; by = t >> 4; }
    __shared__ u16 tile[64][65];
    int c0 = bx * 64, r0 = by * 64;
    for (int i = tid; i < 4096; i += 256) {
        int r = i >> 6, c = i & 63;
        tile[r][c] = f2bf(in[(size_t)(r0 + r) * C + c0 + c]);
    }
    __syncthreads();
    for (int i = tid; i < 4096; i += 256) {
        int r = i >> 6, c = i & 63;
        out[(size_t)(c0 + r) * R + r0 + c] = tile[c][r];
    }
}

// ---------------------------------------------------------------------------
// bf16 transpose with input row stride (V columns of QV): out[c][r]=in[r][c].
// ---------------------------------------------------------------------------
__global__ __launch_bounds__(256) void transpose_bf16_s(const u16* __restrict__ in,
                                                        u16* __restrict__ out,
                                                        int R, int C, int istride) {
    __shared__ u16 tile[64][65];
    int c0 = blockIdx.x * 64, r0 = blockIdx.y * 64;
    in  += (size_t)blockIdx.z * R * istride;
    out += (size_t)blockIdx.z * R * C;
    for (int i = threadIdx.x; i < 4096; i += 256) {
        int r = i >> 6, c = i & 63;
        tile[r][c] = in[(size_t)(r0 + r) * istride + c0 + c];
    }
    __syncthreads();
    for (int i = threadIdx.x; i < 4096; i += 256) {
        int r = i >> 6, c = i & 63;
        out[(size_t)(c0 + r) * R + r0 + c] = tile[c][r];
    }
}

// ---------------------------------------------------------------------------
// LayerNorm over 1024 cols (bf16 in, bf16 out), one row per block.
// ---------------------------------------------------------------------------
__global__ __launch_bounds__(256) void ln_bf16(const u16* __restrict__ x,
                                               const float* __restrict__ g,
                                               const float* __restrict__ be,
                                               u16* __restrict__ out) {
    int row = blockIdx.x, tid = threadIdx.x;
    int lane = tid & 63, wave = tid >> 6;
    u16 e[4]; *(uint2*)e = *(const uint2*)(x + (size_t)row * 1024 + tid * 4);
    float v[4];
#pragma unroll
    for (int i = 0; i < 4; ++i) v[i] = bf2f(e[i]);
    float s1 = v[0] + v[1] + v[2] + v[3];
    float s2 = v[0]*v[0] + v[1]*v[1] + v[2]*v[2] + v[3]*v[3];
#pragma unroll
    for (int mm = 1; mm < 64; mm <<= 1) { s1 += __shfl_xor(s1, mm); s2 += __shfl_xor(s2, mm); }
    __shared__ float a1[4], a2[4];
    if (lane == 0) { a1[wave] = s1; a2[wave] = s2; }
    __syncthreads();
    s1 = a1[0] + a1[1] + a1[2] + a1[3];
    s2 = a2[0] + a2[1] + a2[2] + a2[3];
    float mean = s1 * (1.0f / 1024.0f);
    float var  = s2 * (1.0f / 1024.0f) - mean * mean;
    float rstd = rsqrtf(var + 1e-5f);
#pragma unroll
    for (int i = 0; i < 4; ++i) {
        int c = tid * 4 + i;
        out[(size_t)row * 1024 + c] = f2bf((v[i] - mean) * rstd * g[c] + be[c]);
    }
}

// ---------------------------------------------------------------------------
// GEMM 128xBN. A-LOCAL XCD map: xcd = id&7 owns by in {4*xcd..4*xcd+3}
// (A working set 2 MB per XCD, L2-resident; each A panel read on one XCD).
// Grid 512, bx = 0..15. XOR bank swizzle; coalesced LDS epilogue.
// ---------------------------------------------------------------------------
template <int BN, int ACT, int RES>
__global__ __launch_bounds__(256) void gemm_gl(const u16* __restrict__ A,
                                               const u16* __restrict__ WT,
                                               const float* __restrict__ bias,
                                               const float* __restrict__ resid,
                                               u16* __restrict__ C,
                                               int M, int N, int K) {
    constexpr int JN = BN / 32;
    constexpr int TS = BN + 8;           // padded epilogue stride
    __shared__ u16 lds_a[128 * 64];      // 16 KB (also epilogue tile, 32*TS)
    __shared__ u16 lds_b[BN * 64];
    int tid = threadIdx.x;
    int lane = tid & 63, wave = tid >> 6;
    int l16 = lane & 15, quad = lane >> 4;
    int wm = (wave >> 1) * 64, wn = (wave & 1) * (BN / 2);

    int id = blockIdx.x;
    int u = id >> 3;                     // 0..63
    int by = (id & 7) * 4 + (u & 3);     // 0..31, A-local per XCD
    int bx = u >> 2;                     // 0..15
    int m0 = by * 128, n0 = bx * BN;
    f32x4 acc[4][JN] = {};

    int scol = ((lane & 7) ^ (lane >> 3)) * 8;
    const u16* Ab = A  + (size_t)(m0 + wave * 8 + (lane >> 3)) * K + scol;
    const u16* Bb = WT + (size_t)(n0 + wave * 8 + (lane >> 3)) * K + scol;
    u16* la = lds_a + wave * 512;
    u16* lb = lds_b + wave * 512;
    int xk = (l16 & 7);

    for (int k0 = 0; k0 < K; k0 += 64) {
        __syncthreads();
#pragma unroll
        for (int it = 0; it < 4; ++it)
            gload16(Ab + (size_t)it * 32 * K + k0, la + it * 2048);
#pragma unroll
        for (int it = 0; it < JN; ++it)
            gload16(Bb + (size_t)it * 32 * K + k0, lb + it * 2048);
        __syncthreads();
#pragma unroll
        for (int s = 0; s < 2; ++s) {
            bf16x8 af[4], bfr[JN];
#pragma unroll
            for (int i = 0; i < 4; ++i)
                af[i] = *(const bf16x8*)&lds_a[(wm + i * 16 + l16) * 64 + (((s * 4 + quad) ^ xk) * 8)];
#pragma unroll
            for (int j = 0; j < JN; ++j)
                bfr[j] = *(const bf16x8*)&lds_b[(wn + j * 16 + l16) * 64 + (((s * 4 + quad) ^ xk) * 8)];
#pragma unroll
            for (int i = 0; i < 4; ++i)
#pragma unroll
                for (int j = 0; j < JN; ++j)
                    acc[i][j] = __builtin_amdgcn_mfma_f32_16x16x32_bf16(af[i], bfr[j], acc[i][j], 0, 0, 0);
        }
    }

    // Coalesced epilogue: 4 passes of a 32 x BN bf16 slab through LDS.
    u16* et = lds_a;
    int erow = tid >> 3;                       // 0..31
    int lr0  = (wave >> 1) * 16 + quad * 4;
    float bvj[JN];
#pragma unroll
    for (int j = 0; j < JN; ++j) bvj[j] = bias[n0 + wn + j * 16 + l16];
#pragma unroll
    for (int i = 0; i < 4; ++i) {
        __syncthreads();
#pragma unroll
        for (int j = 0; j < JN; ++j) {
            int col = wn + j * 16 + l16;
#pragma unroll
            for (int r = 0; r < 4; ++r) {
                float v = acc[i][j][r] + bvj[j];
                if (ACT) v = gelu(v);
                if (RES) v += resid[(size_t)(m0 + wm + i * 16 + quad * 4 + r) * N + n0 + col];
                et[(lr0 + r) * TS + col] = f2bf(v);
            }
        }
        __syncthreads();
        int grow = m0 + (erow >> 4) * 64 + i * 16 + (erow & 15);
        if (BN == 128) {
            int ec = (tid & 7) * 16;           // 32 B per thread
            uint4 d0 = *(const uint4*)&et[erow * TS + ec];
            uint4 d1 = *(const uint4*)&et[erow * TS + ec + 8];
            *(uint4*)&C[(size_t)grow * N + n0 + ec]     = d0;
            *(uint4*)&C[(size_t)grow * N + n0 + ec + 8] = d1;
        } else {                               // BN == 64: 16 B per thread
            int ec = (tid & 7) * 8;
            uint4 d0 = *(const uint4*)&et[erow * TS + ec];
            *(uint4*)&C[(size_t)grow * N + n0 + ec] = d0;
        }
    }
}

// ---------------------------------------------------------------------------
// Big-tile GEMM (FF1): 256x128 tile, acc 8x4, coalesced LDS epilogue.
// A-LOCAL XCD map: xcd = id&7 owns by in {2*xcd, 2*xcd+1} (A 1 MB per XCD).
// ---------------------------------------------------------------------------
template <int ACT>
__global__ __launch_bounds__(256, 3) void gemm_big(const u16* __restrict__ A,
                                                   const u16* __restrict__ WT,
                                                   const float* __restrict__ bias,
                                                   u16* __restrict__ C,
                                                   int M, int N, int K) {
    __shared__ u16 lds_a[256 * 64];      // 32 KB (also epilogue tile)
    __shared__ u16 lds_b[128 * 64];      // 16 KB
    int tid = threadIdx.x;
    int lane = tid & 63, wave = tid >> 6;
    int l16 = lane & 15, quad = lane >> 4;
    int wm = (wave >> 1) * 128, wn = (wave & 1) * 64;
    int id = blockIdx.x;
    int u = id >> 3;                     // 0..63
    int by = (id & 7) * 2 + (u & 1);     // 0..15, A-local per XCD
    int bx = u >> 1;                     // 0..31
    int m0 = by * 256, n0 = bx * 128;
    f32x4 acc[8][4] = {};

    int scol = ((lane & 7) ^ (lane >> 3)) * 8;
    const u16* Ab = A  + (size_t)(m0 + wave * 8 + (lane >> 3)) * K + scol;
    const u16* Bb = WT + (size_t)(n0 + wave * 8 + (lane >> 3)) * K + scol;
    u16* la = lds_a + wave * 512;
    u16* lb = lds_b + wave * 512;
    int xk = (l16 & 7);

    for (int k0 = 0; k0 < K; k0 += 64) {
        __syncthreads();
#pragma unroll
        for (int it = 0; it < 8; ++it)
            gload16(Ab + (size_t)it * 32 * K + k0, la + it * 2048);
#pragma unroll
        for (int it = 0; it < 4; ++it)
            gload16(Bb + (size_t)it * 32 * K + k0, lb + it * 2048);
        __syncthreads();
#pragma unroll
        for (int s = 0; s < 2; ++s) {
            bf16x8 bfr[4];
#pragma unroll
            for (int j = 0; j < 4; ++j)
                bfr[j] = *(const bf16x8*)&lds_b[(wn + j * 16 + l16) * 64 + (((s * 4 + quad) ^ xk) * 8)];
#pragma unroll
            for (int i = 0; i < 8; ++i) {
                bf16x8 af = *(const bf16x8*)&lds_a[(wm + i * 16 + l16) * 64 + (((s * 4 + quad) ^ xk) * 8)];
#pragma unroll
                for (int j = 0; j < 4; ++j)
                    acc[i][j] = __builtin_amdgcn_mfma_f32_16x16x32_bf16(af, bfr[j], acc[i][j], 0, 0, 0);
            }
        }
    }

    // Coalesced epilogue: 8 passes of a 32x128 bf16 slab through LDS.
    constexpr int TS = 136;
    u16* et = lds_a;
    int erow = tid >> 3;
    int ec   = (tid & 7) * 16;
    int lr0  = (wave >> 1) * 16 + quad * 4;
    float bvj[4];
#pragma unroll
    for (int j = 0; j < 4; ++j) bvj[j] = bias[n0 + wn + j * 16 + l16];
#pragma unroll
    for (int i = 0; i < 8; ++i) {
        __syncthreads();
#pragma unroll
        for (int j = 0; j < 4; ++j) {
            int col = wn + j * 16 + l16;
#pragma unroll
            for (int r = 0; r < 4; ++r) {
                float v = acc[i][j][r] + bvj[j];
                if (ACT) v = gelu(v);
                et[(lr0 + r) * TS + col] = f2bf(v);
            }
        }
        __syncthreads();
        int grow = m0 + (erow >> 4) * 128 + i * 16 + (erow & 15);
        uint4 d0 = *(const uint4*)&et[erow * TS + ec];
        uint4 d1 = *(const uint4*)&et[erow * TS + ec + 8];
        *(uint4*)&C[(size_t)grow * N + n0 + ec]     = d0;
        *(uint4*)&C[(size_t)grow * N + n0 + ec + 8] = d1;
    }
}

// ---------------------------------------------------------------------------
// FF2 split-K GEMM: 256x128 tiles, split-K=3, bf16 partials, coalesced epi.
// A-local XCD map.
// ---------------------------------------------------------------------------
__global__ __launch_bounds__(256, 3) void gemm_split(const u16* __restrict__ A,
                                                     const u16* __restrict__ WT,
                                                     u16* __restrict__ p0,
                                                     u16* __restrict__ p1,
                                                     u16* __restrict__ p2,
                                                     int M, int N, int K) {
    __shared__ u16 lds_a[256 * 64];
    __shared__ u16 lds_b[128 * 64];
    int tid = threadIdx.x;
    int lane = tid & 63, wave = tid >> 6;
    int l16 = lane & 15, quad = lane >> 4;
    int wm = (wave >> 1) * 128, wn = (wave & 1) * 64;
    int id = blockIdx.x;
    int u = id >> 3;                     // 0..47
    int by = (id & 7) * 2 + (u & 1);     // A-panel owned by xcd = id&7
    int bx = (u >> 1) & 7;
    int slice = u >> 4;                  // 0..2
    int m0 = by * 256, n0 = bx * 128;
    int k_lo = (slice == 0) ? 0 : 64 * (22 + 21 * (slice - 1));
    int k_hi = (slice == 2) ? K : 64 * (22 + 21 * slice);
    u16* P = (slice == 0) ? p0 : (slice == 1) ? p1 : p2;
    f32x4 acc[8][4] = {};

    int scol = ((lane & 7) ^ (lane >> 3)) * 8;
    const u16* Ab = A  + (size_t)(m0 + wave * 8 + (lane >> 3)) * K + scol;
    const u16* Bb = WT + (size_t)(n0 + wave * 8 + (lane >> 3)) * K + scol;
    u16* la = lds_a + wave * 512;
    u16* lb = lds_b + wave * 512;
    int xk = (l16 & 7);

    for (int k0 = k_lo; k0 < k_hi; k0 += 64) {
        __syncthreads();
#pragma unroll
        for (int it = 0; it < 8; ++it)
            gload16(Ab + (size_t)it * 32 * K + k0, la + it * 2048);
#pragma unroll
        for (int it = 0; it < 4; ++it)
            gload16(Bb + (size_t)it * 32 * K + k0, lb + it * 2048);
        __syncthreads();
#pragma unroll
        for (int s = 0; s < 2; ++s) {
            bf16x8 bfr[4];
#pragma unroll
            for (int j = 0; j < 4; ++j)
                bfr[j] = *(const bf16x8*)&lds_b[(wn + j * 16 + l16) * 64 + (((s * 4 + quad) ^ xk) * 8)];
#pragma unroll
            for (int i = 0; i < 8; ++i) {
                bf16x8 af = *(const bf16x8*)&lds_a[(wm + i * 16 + l16) * 64 + (((s * 4 + quad) ^ xk) * 8)];
#pragma unroll
                for (int j = 0; j < 4; ++j)
                    acc[i][j] = __builtin_amdgcn_mfma_f32_16x16x32_bf16(af, bfr[j], acc[i][j], 0, 0, 0);
            }
        }
    }

    constexpr int TS = 136;
    u16* et = lds_a;
    int erow = tid >> 3;
    int ec   = (tid & 7) * 16;
    int lr0  = (wave >> 1) * 16 + quad * 4;
#pragma unroll
    for (int i = 0; i < 8; ++i) {
        __syncthreads();
#pragma unroll
        for (int j = 0; j < 4; ++j) {
            int col = wn + j * 16 + l16;
#pragma unroll
            for (int r = 0; r < 4; ++r)
                et[(lr0 + r) * TS + col] = f2bf(acc[i][j][r]);
        }
        __syncthreads();
        int grow = m0 + (erow >> 4) * 128 + i * 16 + (erow & 15);
        uint4 d0 = *(const uint4*)&et[erow * TS + ec];
        uint4 d1 = *(const uint4*)&et[erow * TS + ec + 8];
        *(uint4*)&P[(size_t)grow * N + n0 + ec]     = d0;
        *(uint4*)&P[(size_t)grow * N + n0 + ec + 8] = d1;
    }
}

// ---------------------------------------------------------------------------
// FF2 reduce: out = x2b(bf16) + p0 + p1 + p2 + b2.  fp32 out.
// ---------------------------------------------------------------------------
__global__ __launch_bounds__(256) void ff2_reduce(const u16* __restrict__ p0,
                                                  const u16* __restrict__ p1,
                                                  const u16* __restrict__ p2,
                                                  const u16* __restrict__ x2b,
                                                  const float* __restrict__ b2,
                                                  float* __restrict__ out) {
    size_t i = ((size_t)blockIdx.x * 256 + threadIdx.x) * 8;
    int col = (int)(i & 1023);
    uint4 a0 = *(const uint4*)&p0[i];
    uint4 a1 = *(const uint4*)&p1[i];
    uint4 a2 = *(const uint4*)&p2[i];
    uint4 ax = *(const uint4*)&x2b[i];
    const u16* e0 = (const u16*)&a0;
    const u16* e1 = (const u16*)&a1;
    const u16* e2 = (const u16*)&a2;
    const u16* ex = (const u16*)&ax;
    float o[8];
#pragma unroll
    for (int e = 0; e < 8; ++e)
        o[e] = bf2f(ex[e]) + bf2f(e0[e]) + bf2f(e1[e]) + bf2f(e2[e]) + b2[col + e];
    *(float4*)&out[i]     = *(float4*)&o[0];
    *(float4*)&out[i + 4] = *(float4*)&o[4];
}

// ---------------------------------------------------------------------------
// Causal attention, Q==K, no-max softmax, BK=128: two 64-key tiles staged
// per barrier pair (half the barriers of BK=64). One 64-row q-tile/block,
// 1024 blocks, longest-first. Last step's causal mask also zeroes the
// overshoot tile when t is even (keys > row -> exp -> 0).
// K swizzle: 8-chunk XOR (row stride 128 B); V staged as [64 d][128 s]
// rows with 16-chunk XOR (row stride 256 B).
// ---------------------------------------------------------------------------
__global__ __launch_bounds__(256) void attn_kernel(const u16* __restrict__ QV,
                                                   const u16* __restrict__ Vt,
                                                   u16* __restrict__ Out) {
    int id = blockIdx.x;
    int slot = id >> 3;
    int hb = (id & 7) + 8 * (slot & 3);
    int t  = 31 - (slot >> 2);
    int h = hb & 15, b = hb >> 4;
    int tid = threadIdx.x;
    int lane = tid & 63, wave = tid >> 6;
    int l16 = lane & 15, quad = lane >> 4;

    __shared__ u16 k_lds[128 * 64];      // 16 KB: 128 keys x 64 d
    __shared__ u16 v_lds[64 * 128];      // 16 KB: 64 d x 128 s
    __shared__ u16 p_lds[4][16 * 136];   // 17 KB: per-wave P (16 x 128, pad)

    bf16x8 ones;
#pragma unroll
    for (int e = 0; e < 8; ++e) ones[e] = (short)0x3F80;

    int srowK = wave * 8 + (lane >> 3);
    int scK   = ((lane & 7) ^ (lane >> 3)) * 8;
    int vrow  = wave * 4 + (lane >> 4);              // 0..15 (V row & 15)
    int scV   = ((lane & 15) ^ vrow) * 8;
    int xk    = (l16 & 7);

    int q0 = t * 64;
    const u16* qp = QV + ((size_t)b * 2048 + q0 + wave * 16 + l16) * 2048 + h * 64;
    bf16x8 qf[2];
    qf[0] = *(const bf16x8*)&qp[quad * 8];
    qf[1] = *(const bf16x8*)&qp[32 + quad * 8];

    f32x4 O[4] = {};
    f32x4 L = {};

    int nsteps = (t >> 1) + 1;
    for (int kt2 = 0; kt2 < nsteps; ++kt2) {
        const u16* kg = QV + ((size_t)b * 2048 + kt2 * 128 + srowK) * 2048 + h * 64 + scK;
        const u16* vg = Vt + ((((size_t)b * 16 + h) * 64) + vrow) * 2048 + kt2 * 128 + scV;
        __syncthreads();
#pragma unroll
        for (int it = 0; it < 4; ++it)
            gload16(kg + (size_t)it * 32 * 2048, k_lds + wave * 512 + it * 2048);
#pragma unroll
        for (int it = 0; it < 4; ++it)
            gload16(vg + (size_t)it * 16 * 2048, v_lds + wave * 512 + it * 2048);
        __syncthreads();

        // S = Q @ K^T : 16 x 128 per wave
        f32x4 S[8] = {};
#pragma unroll
        for (int s = 0; s < 2; ++s)
#pragma unroll
            for (int j = 0; j < 8; ++j) {
                bf16x8 kf = *(const bf16x8*)&k_lds[(j * 16 + l16) * 64 + (((s * 4 + quad) ^ xk) * 8)];
                S[j] = __builtin_amdgcn_mfma_f32_16x16x32_bf16(qf[s], kf, S[j], 0, 0, 0);
            }

        if (kt2 == nsteps - 1) {     // causal mask (also kills overshoot tile)
#pragma unroll
            for (int j = 0; j < 8; ++j) {
                int key = kt2 * 128 + j * 16 + l16;
#pragma unroll
                for (int r = 0; r < 4; ++r)
                    if (key > q0 + wave * 16 + quad * 4 + r) S[j][r] = -1e30f;
            }
        }

#pragma unroll
        for (int j = 0; j < 8; ++j)
#pragma unroll
            for (int r = 0; r < 4; ++r) {
                float pp = __expf(S[j][r] * 0.125f);
                p_lds[wave][(quad * 4 + r) * 136 + j * 16 + l16] = f2bf(pp);
            }

        // O += P @ V ; L += P @ 1   (two 64-key halves)
#pragma unroll
        for (int ktt = 0; ktt < 2; ++ktt)
#pragma unroll
            for (int s = 0; s < 2; ++s) {
                bf16x8 pf = *(const bf16x8*)&p_lds[wave][l16 * 136 + ktt * 64 + s * 32 + quad * 8];
                L = __builtin_amdgcn_mfma_f32_16x16x32_bf16(pf, ones, L, 0, 0, 0);
                int c = ktt * 8 + s * 4 + quad;          // logical 16B chunk
#pragma unroll
                for (int dj = 0; dj < 4; ++dj) {
                    bf16x8 vfr = *(const bf16x8*)&v_lds[(dj * 16 + l16) * 128 + ((c ^ l16) * 8)];
                    O[dj] = __builtin_amdgcn_mfma_f32_16x16x32_bf16(pf, vfr, O[dj], 0, 0, 0);
                }
            }
    }

#pragma unroll
    for (int r = 0; r < 4; ++r) {
        int qg = q0 + wave * 16 + quad * 4 + r;
        float inv = 1.0f / L[r];
#pragma unroll
        for (int dj = 0; dj < 4; ++dj)
            Out[((size_t)b * 2048 + qg) * 1024 + h * 64 + dj * 16 + l16] =
                f2bf(O[dj][r] * inv);
    }
}

// ---------------------------------------------------------------------------
extern "C" void kernel_launch(void* const* d_in, const int* in_sizes, int n_in,
                              void* d_out, int out_size, void* d_ws, size_t ws_size,
                              hipStream_t stream) {
    const float* x   = (const float*)d_in[0];
    const float* Wq  = (const float*)d_in[1];
    const float* bq  = (const float*)d_in[2];
    const float* Wv  = (const float*)d_in[3];
    const float* bv  = (const float*)d_in[4];
    const float* Wo  = (const float*)d_in[5];
    const float* bo  = (const float*)d_in[6];
    const float* W1  = (const float*)d_in[7];
    const float* b1  = (const float*)d_in[8];
    const float* W2  = (const float*)d_in[9];
    const float* b2  = (const float*)d_in[10];
    const float* g1  = (const float*)d_in[11];
    const float* be1 = (const float*)d_in[12];
    const float* g2  = (const float*)d_in[13];
    const float* be2 = (const float*)d_in[14];

    char* ws = (char*)d_ws;
    const size_t MB = 1 << 20;
    // Map:  0-2 WqT | 2-4 WvT | 4-6 WoT | 6-14 W1T | 14-22 W2T
    // 22-30 h1 (LN1 / attn out / h2) | 30-46 QV -> 30-38 x2b after attn
    // 46-54 Vt -> 46-78 ff1 after attn | fp0@0 fp1@22 fp2@38 | bqv@78
    u16*   WqT  = (u16*)(ws + 0  * MB);
    u16*   WvT  = (u16*)(ws + 2  * MB);
    u16*   WoT  = (u16*)(ws + 4  * MB);
    u16*   W1T  = (u16*)(ws + 6  * MB);
    u16*   W2T  = (u16*)(ws + 14 * MB);
    u16*   h1   = (u16*)(ws + 22 * MB);
    u16*   QV   = (u16*)(ws + 30 * MB);
    u16*   x2b  = (u16*)(ws + 30 * MB);
    u16*   Vt   = (u16*)(ws + 46 * MB);
    u16*   ff1  = (u16*)(ws + 46 * MB);
    float* bqv  = (float*)(ws + 78 * MB);
    u16*   fp0  = (u16*)(ws + 0  * MB);
    u16*   fp1  = (u16*)(ws + 22 * MB);
    u16*   fp2  = (u16*)(ws + 38 * MB);

    // 1. fused weight transposes + bias concat + LN1
    prep<<<6920, 256, 0, stream>>>(Wq, Wv, Wo, W1, W2, bq, bv, x, g1, be1,
                                   WqT, WvT, WoT, W1T, W2T, bqv, h1);

    // 2. QV = h1 @ [Wq|Wv] + [bq|bv]   (BN=128, 512 blocks, A-local map)
    gemm_gl<128, 0, 0><<<512, 256, 0, stream>>>(h1, WqT, bqv, nullptr, QV, 4096, 2048, 1024);

    // 3. Vt[b,h,d,s] = transpose of V columns of QV
    transpose_bf16_s<<<dim3(16, 32, 2), 256, 0, stream>>>(QV + 1024, Vt, 2048, 1024, 2048);

    // 4. attention -> h1   (BK=128, 1024 blocks, longest-first)
    attn_kernel<<<1024, 256, 0, stream>>>(QV, Vt, h1);

    // 5. x2b = bf16(x + attn_out@Wo + bo)   (A-local map)
    gemm_gl<64, 0, 1><<<512, 256, 0, stream>>>(h1, WoT, bo, x, x2b, 4096, 1024, 1024);

    // 6. h2 = LN2(x2b) -> h1
    ln_bf16<<<4096, 256, 0, stream>>>(x2b, g2, be2, h1);

    // 7. ff1 = gelu(h2@W1 + b1)   (A-local map)
    gemm_big<1><<<512, 256, 0, stream>>>(h1, W1T, b1, ff1, 4096, 4096, 1024);

    // 8. FF2 split-K partials (A-local map)
    gemm_split<<<384, 256, 0, stream>>>(ff1, W2T, fp0, fp1, fp2, 4096, 1024, 4096);

    // 9. out = x2b + p0+p1+p2 + b2  (fp32)
    ff2_reduce<<<2048, 256, 0, stream>>>(fp0, fp1, fp2, x2b, b2, (float*)d_out);
}